// Round 9
// baseline (288.422 us; speedup 1.0000x reference)
//
#include <hip/hip_runtime.h>
#include <hip/hip_bf16.h>
#include <math.h>

// Problem constants
#define C_IN   2048
#define HID    9
#define NIDX   4096          // 2048 pos + 2048 neg
#define NGRP   32            // 64-ch groups
#define NTILE  16            // 4-ch k-tiles per group
#define ROWS   672           // per (g,b): half0 rows [0,336) + half1 rows [336,672)

// ws layout (dwords)
#define BFRAG_OFF 0                      // uint4[512*2*64] B-fragment table (1 MB)
#define PART_OFF  262144                 // float[32][32][672][9]
#define PART_SZ   ((size_t)NGRP * 32 * ROWS * HID)
#define WS_NEED   (((size_t)PART_OFF + PART_SZ) * 4)    // ~25.8 MB

typedef short  bf16x8 __attribute__((ext_vector_type(8)));
typedef float  f32x4  __attribute__((ext_vector_type(4)));

__device__ __forceinline__ unsigned short bits_of(float v) {
  __hip_bfloat16 h = __float2bfloat16(v);
  return *reinterpret_cast<unsigned short*>(&h);
}

// ---------------------------------------------------------------------------
// P1: build B-fragment table (bf16, MFMA-B layout; proven in R8) and zero the
// atomic-fallback partial region. No lists, no counters.
// lane(n=l&15,q=l>>4) holds B[k=q*8+j][n]; slice0: tap=2q+(j>>2), ch=j&3;
// slice1: tap8 at q==0,j<4. oc>=9 and pad taps are zero.
// ---------------------------------------------------------------------------
__global__ void prep_kernel(const float* __restrict__ Wh,
                            float*       __restrict__ wsf,
                            unsigned*    __restrict__ wsu) {
  int e = blockIdx.x * 256 + threadIdx.x;   // grid 768*256 = 196608
  if (e < 512 * 2 * 64) {
    int lane = e & 63, s = (e >> 6) & 1, tc = e >> 7;
    int n = lane & 15, q = lane >> 4;
    unsigned short h[8];
#pragma unroll
    for (int j = 0; j < 8; j++) {
      float v = 0.f;
      if (n < 9) {
        if (s == 0) {
          int tap = 2 * q + (j >> 2), ch = j & 3;
          v = Wh[(n * C_IN + tc * 4 + ch) * 9 + tap];
        } else if (q == 0 && j < 4) {
          v = Wh[(n * C_IN + tc * 4 + j) * 9 + 8];
        }
      }
      h[j] = bits_of(v);
    }
    uint4 dv;
    dv.x = h[0] | ((unsigned)h[1] << 16);
    dv.y = h[2] | ((unsigned)h[3] << 16);
    dv.z = h[4] | ((unsigned)h[5] << 16);
    dv.w = h[6] | ((unsigned)h[7] << 16);
    ((uint4*)(wsu + BFRAG_OFF))[e] = dv;
  }
  if (e < 32 * ROWS * HID) wsf[PART_OFF + e] = 0.f;   // fallback (g=0) region
}

// ---------------------------------------------------------------------------
// P2: DENSE conv1 via MFMA. grid = (32 groups, 32 images, 2 row-halves),
// 256 threads, 4 blocks/CU. Wave 0 = producer: 4-ch tile -> bf16 ->
// zero-halo [row27][ch4] LDS (3240 B x2, dbuf, flag pipeline). Waves 1-3 =
// consumers: 7 m-tiles each (16 consecutive positions), 3 conflict-free
// ds_read_b64 + 2 MFMA per (m-tile, k-tile). No masks, no lists.
// half0: positions h in [0,12] (325), stages input rows 0..13 at buf rows 1..14.
// half1: positions h in [13,24] (300), stages input rows 12..24 at buf rows 0..12.
// ---------------------------------------------------------------------------
__global__ __launch_bounds__(256, 4) void conv_dense(
    const float* __restrict__ feat,
    const unsigned* __restrict__ wsu,     // B-fragment table
    float* __restrict__ part,             // [32][32][672][9] (or fallback g=0)
    int atomic_mode) {
  __shared__ __align__(16) char stage[2 * 3240];   // 2 x 15 rows x 27 x 4ch bf16
  __shared__ int prod_flag[NTILE];
  __shared__ int cons_cnt[NTILE];

  const int t = threadIdx.x, g = blockIdx.x, b = blockIdx.y, hf = blockIdx.z;
  const int lane = t & 63, wv = t >> 6;

  // zero both halo buffers (ring cells must stay zero) + flags
  for (int i = t; i < 1620; i += 256) ((int*)stage)[i] = 0;
  if (t < NTILE) { prod_flag[t] = 0; cons_cnt[t] = 0; }
  __syncthreads();   // the only barrier

  const int NPOS = hf ? 300 : 325;   // positions this half computes
  const int NMT  = hf ? 19 : 21;     // m-tiles of 16
  const int NEL  = hf ? 325 : 350;   // staged elements per channel
  const int R0   = hf ? 12 : 0;      // first staged input row
  const int BR0  = hf ? 0 : 1;       // buf row of first staged input row

  if (wv == 0) {
    // ---- producer ----
    for (int k = 0; k < NTILE; k++) {
      if (k >= 2)
        while (__hip_atomic_load(&cons_cnt[k - 2], __ATOMIC_ACQUIRE,
                                 __HIP_MEMORY_SCOPE_WORKGROUP) < 3)
          __builtin_amdgcn_s_sleep(1);
      const float* base =
          feat + ((size_t)b * C_IN + g * 64 + k * 4) * 625 + R0 * 25;
      char* bufk = stage + (k & 1) * 3240;
#pragma unroll
      for (int i = 0; i < 6; i++) {
        int idx = i * 64 + lane;
        if (idx < NEL) {
          float f0 = base[idx];
          float f1 = base[625 + idx];
          float f2 = base[1250 + idx];
          float f3 = base[1875 + idx];
          int hr = idx / 25, w = idx - hr * 25;
          int boff = ((BR0 + hr) * 27 + 1 + w) * 8;
          unsigned p01 = bits_of(f0) | ((unsigned)bits_of(f1) << 16);
          unsigned p23 = bits_of(f2) | ((unsigned)bits_of(f3) << 16);
          *(unsigned*)(bufk + boff)     = p01;
          *(unsigned*)(bufk + boff + 4) = p23;
        }
      }
      if (lane == 0)
        __hip_atomic_store(&prod_flag[k], 1, __ATOMIC_RELEASE,
                           __HIP_MEMORY_SCOPE_WORKGROUP);
    }
    return;
  }

  // ---- consumers: waves 1-3, m-tiles (wv-1)+3i ----
  const int n = lane & 15, q = lane >> 4;
  const int t0o = (q == 0) ? -224 : (q == 1) ? -208 : (q == 2) ? 0   : 208;
  const int t1o = (q == 0) ? -216 : (q == 1) ? -8   : (q == 2) ? 8   : 216;

  int a0[7], a1[7], a8[7], mt[7];
#pragma unroll
  for (int i = 0; i < 7; i++) {
    mt[i] = (wv - 1) + 3 * i;
    int pl = mt[i] * 16 + n;
    if (pl >= NPOS) pl = NPOS - 1;          // clamped lanes read valid rows
    int hl = pl / 25, w = pl - hl * 25;
    int cen = ((hl + 1) * 27 + w + 1) * 8;  // min 224 -> +t0o >= 0
    a0[i] = cen + t0o;
    a1[i] = cen + t1o;
    a8[i] = cen + 224;
  }

  f32x4 acc[7];
#pragma unroll
  for (int i = 0; i < 7; i++) acc[i] = (f32x4){0.f, 0.f, 0.f, 0.f};

  const uint4* btab = (const uint4*)(wsu + BFRAG_OFF);

  for (int k = 0; k < NTILE; k++) {
    const int tc = g * NTILE + k;
    // prefetch B fragments (flag-independent) so latency hides under the spin
    uint4 raw0 = btab[(tc * 2 + 0) * 64 + lane];
    uint4 raw1 = btab[(tc * 2 + 1) * 64 + lane];
    while (__hip_atomic_load(&prod_flag[k], __ATOMIC_ACQUIRE,
                             __HIP_MEMORY_SCOPE_WORKGROUP) == 0)
      __builtin_amdgcn_s_sleep(1);
    const char* bufk = stage + (k & 1) * 3240;
    bf16x8 bf0 = __builtin_bit_cast(bf16x8, raw0);
    bf16x8 bf1 = __builtin_bit_cast(bf16x8, raw1);
#pragma unroll
    for (int i = 0; i < 7; i++) {
      if (mt[i] < NMT) {
        int2 lo = *(const int2*)(bufk + a0[i]);   // taps 2q   x ch0-3
        int2 hi = *(const int2*)(bufk + a1[i]);   // taps 2q+1 x ch0-3
        int2 r8 = *(const int2*)(bufk + a8[i]);   // tap 8     x ch0-3
        int4 av0 = {lo.x, lo.y, hi.x, hi.y};
        acc[i] = __builtin_amdgcn_mfma_f32_16x16x32_bf16(
            __builtin_bit_cast(bf16x8, av0), bf0, acc[i], 0, 0, 0);
        int4 av1 = {r8.x, r8.y, 0, 0};
        acc[i] = __builtin_amdgcn_mfma_f32_16x16x32_bf16(
            __builtin_bit_cast(bf16x8, av1), bf1, acc[i], 0, 0, 0);
      }
    }
    if (lane == 0)
      __hip_atomic_fetch_add(&cons_cnt[k], 1, __ATOMIC_RELEASE,
                             __HIP_MEMORY_SCOPE_WORKGROUP);
  }

  // epilogue: D[row=q*4+reg = position, col=n = oc]
  if (n < 9) {
    float* pp = part + (((size_t)(atomic_mode ? 0 : g) * 32 + b) * ROWS +
                        hf * 336) * HID;
#pragma unroll
    for (int i = 0; i < 7; i++) {
      if (mt[i] >= NMT) continue;
#pragma unroll
      for (int reg = 0; reg < 4; reg++) {
        int pl = mt[i] * 16 + q * 4 + reg;
        if (pl < NPOS) {
          float v = acc[i][reg];
          if (atomic_mode) atomicAdd(&pp[pl * HID + n], v);
          else             pp[pl * HID + n] = v;
        }
      }
    }
  }
}

// ---------------------------------------------------------------------------
// P3: fused plane-reduce + bias + ReLU + heads + box transform. 4096 threads.
// out layout: [0,2048) pos_conf | [2048,4096) neg_conf |
//             [4096,12288) pos_offsets | [12288,20480) proposals
// ---------------------------------------------------------------------------
__global__ void heads_kernel(const float* __restrict__ part,
                             int nplanes,
                             const int*   __restrict__ pos_idx,
                             const int*   __restrict__ neg_idx,
                             const float* __restrict__ pos_ancs,
                             const float* __restrict__ bh,
                             const float* __restrict__ Wc,
                             const float* __restrict__ bc,
                             const float* __restrict__ Wr,
                             const float* __restrict__ br,
                             float*       __restrict__ out) {
  int i = blockIdx.x * 256 + threadIdx.x;
  if (i >= NIDX) return;
  int flat = (i < 2048) ? pos_idx[i] : neg_idx[i - 2048];
  int anc = flat % 9;
  int pw  = flat / 9;
  int b   = pw / 625;
  int p   = pw - b * 625;
  int hf  = (p >= 325) ? 1 : 0;
  int row = b * ROWS + hf * 336 + (p - hf * 325);
  float xr[9];
#pragma unroll
  for (int j = 0; j < 9; j++) xr[j] = bh[j];
  for (int gp = 0; gp < nplanes; gp++) {
    const float* pp = part + ((size_t)gp * 32 * ROWS + row) * HID;
#pragma unroll
    for (int j = 0; j < 9; j++) xr[j] += pp[j];
  }
#pragma unroll
  for (int j = 0; j < 9; j++) xr[j] = xr[j] > 0.f ? xr[j] : 0.f;
  float conf = bc[anc];
#pragma unroll
  for (int j = 0; j < 9; j++) conf += xr[j] * Wc[anc * 9 + j];
  out[i] = conf;
  if (i < 2048) {
    float off[4];
#pragma unroll
    for (int k = 0; k < 4; k++) {
      float sacc = br[anc * 4 + k];
#pragma unroll
      for (int j = 0; j < 9; j++) sacc += xr[j] * Wr[(anc * 4 + k) * 9 + j];
      off[k] = sacc;
      out[4096 + i * 4 + k] = sacc;
    }
    float x1 = pos_ancs[i * 4 + 0], y1 = pos_ancs[i * 4 + 1];
    float x2 = pos_ancs[i * 4 + 2], y2 = pos_ancs[i * 4 + 3];
    float cx = (x1 + x2) * 0.5f, cy = (y1 + y2) * 0.5f;
    float w = x2 - x1, h = y2 - y1;
    float ncx = cx + off[0] * w, ncy = cy + off[1] * h;
    float nw = w * expf(off[2]), nh = h * expf(off[3]);
    out[12288 + i * 4 + 0] = ncx - nw * 0.5f;
    out[12288 + i * 4 + 1] = ncy - nh * 0.5f;
    out[12288 + i * 4 + 2] = ncx + nw * 0.5f;
    out[12288 + i * 4 + 3] = ncy + nh * 0.5f;
  }
}

// ---------------------------------------------------------------------------
extern "C" void kernel_launch(void* const* d_in, const int* in_sizes, int n_in,
                              void* d_out, int out_size, void* d_ws, size_t ws_size,
                              hipStream_t stream) {
  const float* feat     = (const float*)d_in[0];
  const int*   pos_idx  = (const int*)d_in[1];
  const int*   neg_idx  = (const int*)d_in[2];
  const float* pos_ancs = (const float*)d_in[3];
  const float* Wh       = (const float*)d_in[4];
  const float* bh       = (const float*)d_in[5];
  const float* Wc       = (const float*)d_in[6];
  const float* bc       = (const float*)d_in[7];
  const float* Wr       = (const float*)d_in[8];
  const float* br       = (const float*)d_in[9];
  float* out = (float*)d_out;

  float*    wsf  = (float*)d_ws;
  unsigned* wsu  = (unsigned*)d_ws;
  float*    part = wsf + PART_OFF;

  const bool small_ws = (ws_size < WS_NEED);   // constant across calls

  prep_kernel<<<768, 256, 0, stream>>>(Wh, wsf, wsu);
  conv_dense<<<dim3(NGRP, 32, 2), 256, 0, stream>>>(
      feat, wsu, part, small_ws ? 1 : 0);
  heads_kernel<<<16, 256, 0, stream>>>(part, small_ws ? 1 : NGRP,
                                       pos_idx, neg_idx, pos_ancs,
                                       bh, Wc, bc, Wr, br, out);
}